// Round 13
// baseline (1408.613 us; speedup 1.0000x reference)
//
#include <hip/hip_runtime.h>
#include <math.h>

// Problem constants (derived from setup_inputs()).
#define B_  16
#define S_  4096
#define D_  128
#define R0_ 0
#define R1_ 3583
#define P_  3584          // R1_-R0_+1
#define MERGE_ 4
#define K_  896           // P_/MERGE_
#define MAXTOK_ 1024      // ceil(S_/MERGE_)
#define PAD_ 128          // MAXTOK_-K_
#define TAILSTART_ 3585   // vision_end(=R1_+1)+1
#define TAILLEN_ 510      // (S_-1) - TAILSTART_
#define TOK_ 1534         // MAXTOK_ + TAILLEN_
#define ITERS_ 10
#define EPS_ 1e-12f

#define NG_ 56            // K_/16 col-groups
#define NGH_ 28           // per k-half
#define BP_ (B_ * P_)

typedef short bf16x8 __attribute__((ext_vector_type(8)));
typedef float f32x4 __attribute__((ext_vector_type(4)));

__device__ __forceinline__ unsigned short f2bh(float f) {   // fp32 -> bf16 RNE
  unsigned u = __float_as_uint(f);
  unsigned r = u + 0x7fffu + ((u >> 16) & 1u);
  return (unsigned short)(r >> 16);
}
__device__ __forceinline__ float bh2f(unsigned short h) {
  return __uint_as_float(((unsigned)h) << 16);
}

// split v[8] into 3-term bf16: v = h + m + l + O(2^-27 v)
__device__ __forceinline__ void split3(const float* v, bf16x8& h, bf16x8& m, bf16x8& l) {
#pragma unroll
  for (int i = 0; i < 8; ++i) {
    unsigned short hh = f2bh(v[i]); float r1 = v[i] - bh2f(hh);
    unsigned short mm = f2bh(r1);   float r2 = r1 - bh2f(mm);
    unsigned short ll = f2bh(r2);
    h[i] = (short)hh; m[i] = (short)mm; l[i] = (short)ll;
  }
}

// ---------------- normalize rows ----------------
__global__ __launch_bounds__(256) void normalize_kernel(const float* __restrict__ hs,
                                                        float* __restrict__ xn) {
  int row = blockIdx.x * 4 + (threadIdx.x >> 6);
  int lane = threadIdx.x & 63;
  if (row >= B_ * P_) return;
  int b = row / P_, p = row % P_;
  float2 v = *reinterpret_cast<const float2*>(hs + ((size_t)b * S_ + R0_ + p) * D_ + lane * 2);
  float ss = v.x * v.x + v.y * v.y;
#pragma unroll
  for (int off = 32; off; off >>= 1) ss += __shfl_xor(ss, off);
  float denom = fmaxf(sqrtf(ss), EPS_);
  float2 nv; nv.x = v.x / denom; nv.y = v.y / denom;
  *reinterpret_cast<float2*>(xn + (size_t)row * D_ + lane * 2) = nv;
}

// ---------------- init centroids (every 4th point) + c2 ----------------
__global__ __launch_bounds__(256) void init_cent_kernel(const float* __restrict__ xn,
                                                        float* __restrict__ c,
                                                        float* __restrict__ c2) {
  int w = blockIdx.x * 4 + (threadIdx.x >> 6);
  int lane = threadIdx.x & 63;
  if (w >= B_ * K_) return;
  int b = w / K_, k = w % K_;
  float2 v = *reinterpret_cast<const float2*>(xn + ((size_t)b * P_ + k * MERGE_) * D_ + lane * 2);
  *reinterpret_cast<float2*>(c + ((size_t)w) * D_ + lane * 2) = v;
  float ss = v.x * v.x + v.y * v.y;
#pragma unroll
  for (int off = 32; off; off >>= 1) ss += __shfl_xor(ss, off);
  if (lane == 0) c2[w] = ss;
}

// ---------------- pack centroids into fragment-major 3-term bf16 ----------------
// bp[b][g][s][t][lane] (16B units): lane -> col=g*16+(lane&15), d=32s+8*(lane>>4)+i
__global__ __launch_bounds__(256) void pack_B_kernel(const float* __restrict__ cc,
                                                     bf16x8* __restrict__ bp) {
  int job = blockIdx.x * 4 + (threadIdx.x >> 6);   // (b,g,s)
  int lane = threadIdx.x & 63;
  if (job >= B_ * NG_ * 4) return;
  int b = job / (NG_ * 4);
  int rem = job % (NG_ * 4);
  int g = rem >> 2, s = rem & 3;
  int col = g * 16 + (lane & 15);
  int d0 = s * 32 + (lane >> 4) * 8;
  const float* src = cc + ((size_t)b * K_ + col) * D_ + d0;
  float v[8];
  *reinterpret_cast<float4*>(&v[0]) = *reinterpret_cast<const float4*>(src);
  *reinterpret_cast<float4*>(&v[4]) = *reinterpret_cast<const float4*>(src + 4);
  bf16x8 h, m, l;
  split3(v, h, m, l);
  size_t base = (size_t)b * (NG_ * 4 * 3 * 64) + (size_t)((g * 4 + s) * 3) * 64;
  bp[base + lane] = h;
  bp[base + 64 + lane] = m;
  bp[base + 128 + lane] = l;
}

// ---------------- assign: split-bf16 MFMA GEMM + per-half argmin ----------------
// dv = c2 - 2*dot (x2 dropped: row-constant). k-split x2: block handles 64 rows x
// 28 g; partial (bestd,bestk) -> pd/pk[kh]. Grid 1792 = 8 XCD x 224 -> 14 waves/CU.
__global__ __launch_bounds__(128, 2) void assign_mfma_kernel(const float* __restrict__ xn,
                                                             const bf16x8* __restrict__ bp,
                                                             const float* __restrict__ c2,
                                                             float* __restrict__ pd,
                                                             int* __restrict__ pk) {
  int bid = blockIdx.x;
  int xcd = bid & 7;
  int idx = bid >> 3;                  // 0..223
  int b = 2 * xcd + (idx >= 112 ? 1 : 0);
  int inner = (idx >= 112) ? idx - 112 : idx;   // 0..111
  int mb = inner >> 1;                 // 0..55
  int kh = inner & 1;                  // k-half
  int g0 = kh * NGH_;
  int tid = threadIdx.x;
  int widx = tid >> 6, lane = tid & 63;
  int l15 = lane & 15, lg = lane >> 4; // lg 0..3
  int base_row = mb * 64 + widx * 32;

  // ---- load + split A fragments (once): fa[mi][s][t] ----
  bf16x8 fa[2][4][3];
  {
    const float* xb = xn + (size_t)b * P_ * D_;
#pragma unroll
    for (int mi = 0; mi < 2; ++mi)
#pragma unroll
      for (int s = 0; s < 4; ++s) {
        const float* src = xb + (size_t)(base_row + mi * 16 + l15) * D_ + s * 32 + lg * 8;
        float v[8];
        *reinterpret_cast<float4*>(&v[0]) = *reinterpret_cast<const float4*>(src);
        *reinterpret_cast<float4*>(&v[4]) = *reinterpret_cast<const float4*>(src + 4);
        split3(v, fa[mi][s][0], fa[mi][s][1], fa[mi][s][2]);
      }
  }

  float bestd[8]; int bestk[8];
#pragma unroll
  for (int i = 0; i < 8; ++i) { bestd[i] = 3.4e38f; bestk[i] = 0; }

  const bf16x8* bpb = bp + (size_t)b * (NG_ * 4 * 3 * 64);
  const float* c2b = c2 + (size_t)b * K_;

#define MFMA_(A, Bf, C) __builtin_amdgcn_mfma_f32_16x16x32_bf16(A, Bf, C, 0, 0, 0)
#define SIX(accv, mi, s, FB)                      \
  accv = MFMA_(fa[mi][s][0], FB[s][0], accv);     \
  accv = MFMA_(fa[mi][s][0], FB[s][1], accv);     \
  accv = MFMA_(fa[mi][s][1], FB[s][0], accv);     \
  accv = MFMA_(fa[mi][s][0], FB[s][2], accv);     \
  accv = MFMA_(fa[mi][s][2], FB[s][0], accv);     \
  accv = MFMA_(fa[mi][s][1], FB[s][1], accv);

#define LOADFB(FB, C2V, G) do {                                            \
    int g_ = (G);                                                          \
    for (int s_ = 0; s_ < 4; ++s_)                                         \
      for (int t_ = 0; t_ < 3; ++t_)                                       \
        FB[s_][t_] = bpb[(size_t)((g_ * 4 + s_) * 3 + t_) * 64 + lane];    \
    C2V = c2b[g_ * 16 + l15];                                              \
  } while (0)

#define COMPUTE(FB, C2V, G) do {                                           \
    f32x4 a00 = {0.f,0.f,0.f,0.f}, a01 = {0.f,0.f,0.f,0.f};                \
    f32x4 a10 = {0.f,0.f,0.f,0.f}, a11 = {0.f,0.f,0.f,0.f};                \
    SIX(a00, 0, 0, FB) SIX(a10, 1, 0, FB) SIX(a01, 0, 2, FB) SIX(a11, 1, 2, FB) \
    SIX(a00, 0, 1, FB) SIX(a10, 1, 1, FB) SIX(a01, 0, 3, FB) SIX(a11, 1, 3, FB) \
    int kcol = (G) * 16 + l15;                                             \
    for (int r_ = 0; r_ < 4; ++r_) {                                       \
      float d0v = fmaf(-2.f, a00[r_] + a01[r_], C2V);                      \
      if (d0v < bestd[r_]) { bestd[r_] = d0v; bestk[r_] = kcol; }          \
      float d1v = fmaf(-2.f, a10[r_] + a11[r_], C2V);                      \
      if (d1v < bestd[4 + r_]) { bestd[4 + r_] = d1v; bestk[4 + r_] = kcol; } \
    }                                                                      \
  } while (0)

  bf16x8 fbA[4][3], fbB[4][3];
  float c2A, c2B;
  LOADFB(fbA, c2A, g0);
  for (int g = g0; g < g0 + NGH_; g += 2) {
    LOADFB(fbB, c2B, g + 1);
    COMPUTE(fbA, c2A, g);
    int gn = (g + 2 < g0 + NGH_) ? g + 2 : g0;    // last prefetch harmless
    LOADFB(fbA, c2A, gn);
    COMPUTE(fbB, c2B, g + 1);
  }
#undef COMPUTE
#undef LOADFB
#undef SIX
#undef MFMA_

  // reduce across the 16 lanes sharing each row (same lg, varying l15)
#pragma unroll
  for (int slot = 0; slot < 8; ++slot) {
    float bd = bestd[slot]; int bk = bestk[slot];
#pragma unroll
    for (int off = 8; off; off >>= 1) {
      float od = __shfl_down(bd, off, 16);
      int   ok = __shfl_down(bk, off, 16);
      if (od < bd || (od == bd && ok < bk)) { bd = od; bk = ok; }
    }
    if (l15 == 0) {
      int mi = slot >> 2, r = slot & 3;
      int row = base_row + mi * 16 + 4 * lg + r;   // C/D: row=(lane>>4)*4+r
      size_t o = (size_t)kh * BP_ + (size_t)b * P_ + row;
      pd[o] = bd;
      pk[o] = bk;
    }
  }
}

// ---------------- merge k-halves: global argmin + labels + histogram ----------------
// k0 < 448 <= k1 always, so first-index tie-break == take k1 only on strict <.
// cnt must be zeroed before this kernel. Counts are order-independent (deterministic).
__global__ __launch_bounds__(256) void merge_kernel(const float* __restrict__ pd,
                                                    const int* __restrict__ pk,
                                                    int* __restrict__ labels,
                                                    int* __restrict__ cnt) {
  int i = blockIdx.x * 256 + threadIdx.x;
  if (i >= BP_) return;
  float d0 = pd[i], d1 = pd[BP_ + i];
  int k = (d1 < d0) ? pk[BP_ + i] : pk[i];
  labels[i] = k;
  int b = i / P_;
  atomicAdd(&cnt[b * K_ + k], 1);
}

// ---------------- scan + DETERMINISTIC stable scatter (one block per batch) ----------------
// order[] holds each cluster's members in ASCENDING point-index order, bit-identical
// every run: chunk-sequential, wave-serialized commits, in-wave stable rank via shfl.
__global__ __launch_bounds__(1024) void scan_scatter_kernel(const int* __restrict__ cnt,
                                                            const int* __restrict__ labels,
                                                            int* __restrict__ starts,
                                                            int* __restrict__ order) {
  __shared__ int sm[1024];
  __shared__ int cur[K_];
  int b = blockIdx.x, t = threadIdx.x;
  int lane = t & 63, widx = t >> 6;          // 16 waves
  int v = (t < K_) ? cnt[b * K_ + t] : 0;
  sm[t] = v;
  __syncthreads();
  for (int off = 1; off < 1024; off <<= 1) {
    int u = (t >= off) ? sm[t - off] : 0;
    __syncthreads();
    sm[t] += u;
    __syncthreads();
  }
  if (t < K_) { int ex = sm[t] - v; starts[b * K_ + t] = ex; cur[t] = ex; }
  __syncthreads();

  // 4 chunks of 1024 points (last chunk: 512 valid = waves 0..7, wave-aligned)
  for (int r = 0; r < 4; ++r) {
    int p = r * 1024 + t;
    bool valid = (p < P_);
    int lab = valid ? labels[b * P_ + p] : -1;
    // stable in-wave rank by lane order
    int rank = 0, tot = 0;
    for (int j = 0; j < 64; ++j) {
      int labj = __shfl(lab, j);
      if (labj == lab) { tot++; if (j < lane) rank++; }
    }
    // waves commit in order -> global order = ascending p
    for (int w = 0; w < 16; ++w) {
      if (widx == w && valid) {
        int base = cur[lab];
        order[b * P_ + base + rank] = p;
        if (rank == tot - 1) cur[lab] = base + tot;   // unique lane per label
      }
      __syncthreads();
    }
  }
}

// ---------------- centroid update (mean of members; keep old if empty) ----------------
__global__ __launch_bounds__(256) void update_kernel(const float* __restrict__ xn,
                                                     const int* __restrict__ order,
                                                     const int* __restrict__ cnt,
                                                     const int* __restrict__ starts,
                                                     float* __restrict__ c,
                                                     float* __restrict__ c2) {
  int w = blockIdx.x * 4 + (threadIdx.x >> 6);
  int lane = threadIdx.x & 63;
  if (w >= B_ * K_) return;
  int b = w / K_;
  int n = cnt[w], st = starts[w];
  const float* xb = xn + (size_t)b * P_ * D_;
  float2 acc = make_float2(0.f, 0.f);
  for (int i = 0; i < n; ++i) {
    int p = order[b * P_ + st + i];
    float2 v = *reinterpret_cast<const float2*>(xb + (size_t)p * D_ + lane * 2);
    acc.x += v.x; acc.y += v.y;
  }
  float* cp = c + (size_t)w * D_ + lane * 2;
  float2 cur;
  if (n > 0) {
    float dn = (float)n;
    cur.x = acc.x / dn; cur.y = acc.y / dn;
    *reinterpret_cast<float2*>(cp) = cur;
  } else {
    cur = *reinterpret_cast<const float2*>(cp);
  }
  float ss = cur.x * cur.x + cur.y * cur.y;
#pragma unroll
  for (int off = 32; off; off >>= 1) ss += __shfl_xor(ss, off);
  if (lane == 0) c2[w] = ss;
}

// ---------------- final pooling: mean -> l2 normalize -> out[:, PAD_+k] ----------------
__global__ __launch_bounds__(256) void pool_kernel(const float* __restrict__ xn,
                                                   const int* __restrict__ order,
                                                   const int* __restrict__ cnt,
                                                   const int* __restrict__ starts,
                                                   float* __restrict__ outh,
                                                   float* __restrict__ outm) {
  int w = blockIdx.x * 4 + (threadIdx.x >> 6);
  int lane = threadIdx.x & 63;
  if (w >= B_ * K_) return;
  int b = w / K_, k = w % K_;
  int n = cnt[w], st = starts[w];
  const float* xb = xn + (size_t)b * P_ * D_;
  float2 acc = make_float2(0.f, 0.f);
  for (int i = 0; i < n; ++i) {
    int p = order[b * P_ + st + i];
    float2 v = *reinterpret_cast<const float2*>(xb + (size_t)p * D_ + lane * 2);
    acc.x += v.x; acc.y += v.y;
  }
  float dn = (float)(n > 0 ? n : 1);
  float2 mean; mean.x = acc.x / dn; mean.y = acc.y / dn;
  float ss = mean.x * mean.x + mean.y * mean.y;
#pragma unroll
  for (int off = 32; off; off >>= 1) ss += __shfl_xor(ss, off);
  float denom = fmaxf(sqrtf(ss), EPS_);
  float2 pv;
  if (n > 0) { pv.x = mean.x / denom; pv.y = mean.y / denom; }
  else       { pv.x = 0.f; pv.y = 0.f; }
  int tok = PAD_ + k;
  *reinterpret_cast<float2*>(outh + ((size_t)b * TOK_ + tok) * D_ + lane * 2) = pv;
  if (lane == 0) outm[b * TOK_ + tok] = (n > 0) ? 1.f : 0.f;
}

// ---------------- zeros prefix + tail copy + masks ----------------
__global__ __launch_bounds__(256) void assemble_kernel(const float* __restrict__ hs,
                                                       float* __restrict__ outh,
                                                       float* __restrict__ outm) {
  const int ROWS = PAD_ + TAILLEN_;   // 638
  int w = blockIdx.x * 4 + (threadIdx.x >> 6);
  int lane = threadIdx.x & 63;
  if (w >= B_ * ROWS) return;
  int b = w / ROWS, r = w % ROWS;
  int tok; float2 v; float m;
  if (r < PAD_) {
    tok = r; v = make_float2(0.f, 0.f); m = 0.f;
  } else {
    tok = MAXTOK_ + (r - PAD_);
    v = *reinterpret_cast<const float2*>(hs + ((size_t)b * S_ + TAILSTART_ + (r - PAD_)) * D_ + lane * 2);
    m = 1.f;
  }
  *reinterpret_cast<float2*>(outh + ((size_t)b * TOK_ + tok) * D_ + lane * 2) = v;
  if (lane == 0) outm[b * TOK_ + tok] = m;
}

extern "C" void kernel_launch(void* const* d_in, const int* in_sizes, int n_in,
                              void* d_out, int out_size, void* d_ws, size_t ws_size,
                              hipStream_t stream) {
  const float* hs = (const float*)d_in[0];
  float* outh = (float*)d_out;
  float* outm = outh + (size_t)B_ * TOK_ * D_;

  char* wsb = (char*)d_ws;
  size_t off = 0;
  auto alloc = [&](size_t bytes) -> void* {
    void* p = wsb + off;
    off += (bytes + 255) & ~(size_t)255;
    return p;
  };
  float*  xn     = (float*) alloc((size_t)B_ * P_ * D_ * sizeof(float));        // 29.4 MB
  float*  cc     = (float*) alloc((size_t)B_ * K_ * D_ * sizeof(float));        // 7.34 MB
  bf16x8* bpack  = (bf16x8*)alloc((size_t)B_ * NG_ * 4 * 3 * 64 * 16);          // 11.0 MB
  float*  c2     = (float*) alloc((size_t)B_ * K_ * sizeof(float));
  float*  pd     = (float*) alloc((size_t)2 * BP_ * sizeof(float));
  int*    pk     = (int*)   alloc((size_t)2 * BP_ * sizeof(int));
  int*    labels = (int*)   alloc((size_t)BP_ * sizeof(int));
  int*    cnt    = (int*)   alloc((size_t)B_ * K_ * sizeof(int));
  int*    starts = (int*)   alloc((size_t)B_ * K_ * sizeof(int));
  int*    order  = (int*)   alloc((size_t)BP_ * sizeof(int));
  (void)ws_size; (void)in_sizes; (void)n_in; (void)out_size;

  normalize_kernel<<<(B_ * P_ + 3) / 4, 256, 0, stream>>>(hs, xn);
  init_cent_kernel<<<(B_ * K_ + 3) / 4, 256, 0, stream>>>(xn, cc, c2);
  pack_B_kernel<<<B_ * NG_, 256, 0, stream>>>(cc, bpack);

  for (int it = 0; it < ITERS_; ++it) {
    hipMemsetAsync(cnt, 0, (size_t)B_ * K_ * sizeof(int), stream);
    assign_mfma_kernel<<<1792, 128, 0, stream>>>(xn, bpack, c2, pd, pk);
    merge_kernel<<<(BP_ + 255) / 256, 256, 0, stream>>>(pd, pk, labels, cnt);
    scan_scatter_kernel<<<B_, 1024, 0, stream>>>(cnt, labels, starts, order);
    update_kernel<<<(B_ * K_ + 3) / 4, 256, 0, stream>>>(xn, order, cnt, starts, cc, c2);
    pack_B_kernel<<<B_ * NG_, 256, 0, stream>>>(cc, bpack);
  }

  // final labels + pooling
  hipMemsetAsync(cnt, 0, (size_t)B_ * K_ * sizeof(int), stream);
  assign_mfma_kernel<<<1792, 128, 0, stream>>>(xn, bpack, c2, pd, pk);
  merge_kernel<<<(BP_ + 255) / 256, 256, 0, stream>>>(pd, pk, labels, cnt);
  scan_scatter_kernel<<<B_, 1024, 0, stream>>>(cnt, labels, starts, order);
  pool_kernel<<<(B_ * K_ + 3) / 4, 256, 0, stream>>>(xn, order, cnt, starts, outh, outm);
  assemble_kernel<<<(B_ * (PAD_ + TAILLEN_) + 3) / 4, 256, 0, stream>>>(hs, outh, outm);
}